// Round 10
// baseline (511.741 us; speedup 1.0000x reference)
//
#include <hip/hip_runtime.h>
#include <hip/hip_bf16.h>

#define BB 4
#define CC 256
#define HW 4096
#define DD 128

typedef __attribute__((ext_vector_type(8))) short bf16x8;
typedef __attribute__((ext_vector_type(4))) float f32x4;

static __device__ __forceinline__ void ld4(float* dst, const float* src) {
  float4 t = *(const float4*)src;
  dst[0] = t.x; dst[1] = t.y; dst[2] = t.z; dst[3] = t.w;
}

// float -> bf16 (RNE) raw bits
static __device__ __forceinline__ short f2b(float f) {
  unsigned u = __float_as_uint(f);
  u += 0x7fffu + ((u >> 16) & 1u);
  return (short)(u >> 16);
}
static __device__ __forceinline__ unsigned pk2(float lo, float hi) {
  return (unsigned)(unsigned short)f2b(lo) | ((unsigned)(unsigned short)f2b(hi) << 16);
}

// ---------------- K1: q/k/v 1x1 conv. GEMM (128x256)@(256x4096) per (which,b)
__global__ __launch_bounds__(256) void k_qkv(
    const float* __restrict__ src, const float* __restrict__ tgt,
    const float* __restrict__ Wq, const float* __restrict__ bq,
    const float* __restrict__ Wk, const float* __restrict__ bk,
    const float* __restrict__ Wv, const float* __restrict__ bv,
    float* __restrict__ qw, float* __restrict__ kwp, float* __restrict__ vwp)
{
  __shared__ float Wt[32][132];
  __shared__ float Xs[32][68];
  const int tid = threadIdx.x;
  const int tx = tid & 15, ty = tid >> 4;
  const int p0 = blockIdx.x * 64;
  const int which = blockIdx.y;
  const int b = blockIdx.z;
  const float* X    = (which == 0) ? src : tgt;
  const float* Wm   = (which == 0) ? Wq : (which == 1) ? Wk : Wv;
  const float* bias = (which == 0) ? bq : (which == 1) ? bk : bv;
  float* out        = (which == 0) ? qw : (which == 1) ? kwp : vwp;

  float acc[8][4];
#pragma unroll
  for (int i = 0; i < 8; ++i)
#pragma unroll
    for (int j = 0; j < 4; ++j) acc[i][j] = 0.f;

  for (int kk = 0; kk < CC; kk += 32) {
    __syncthreads();
#pragma unroll
    for (int u = 0; u < 4; ++u) {
      int e = tid + 256 * u;
      int c4 = (e & 7) * 4, r = e >> 3;
      float w[4]; ld4(w, &Wm[r * CC + kk + c4]);
      Wt[c4 + 0][r] = w[0]; Wt[c4 + 1][r] = w[1];
      Wt[c4 + 2][r] = w[2]; Wt[c4 + 3][r] = w[3];
    }
#pragma unroll
    for (int u = 0; u < 2; ++u) {
      int e = tid + 256 * u;
      int p4 = (e & 15) * 4, c = e >> 4;
      *(float4*)&Xs[c][p4] = *(const float4*)&X[(b * CC + kk + c) * HW + p0 + p4];
    }
    __syncthreads();
#pragma unroll 4
    for (int c = 0; c < 32; ++c) {
      float wa[8], xb[4];
      ld4(wa, &Wt[c][ty * 8]); ld4(wa + 4, &Wt[c][ty * 8 + 4]);
      ld4(xb, &Xs[c][tx * 4]);
#pragma unroll
      for (int rr = 0; rr < 8; ++rr)
#pragma unroll
        for (int pp = 0; pp < 4; ++pp) acc[rr][pp] += wa[rr] * xb[pp];
    }
  }
#pragma unroll
  for (int rr = 0; rr < 8; ++rr) {
    int r = ty * 8 + rr;
    float bv_ = bias[r];
    float4 o4 = make_float4(acc[rr][0] + bv_, acc[rr][1] + bv_,
                            acc[rr][2] + bv_, acc[rr][3] + bv_);
    *(float4*)&out[(b * DD + r) * HW + p0 + tx * 4] = o4;
  }
}

// ---------------- K1b: transpose+cast q,k: (B,128,HW) f32 -> (B,HW,128) bf16
__global__ __launch_bounds__(256) void k_qkb(
    const float* __restrict__ qw, const float* __restrict__ kw,
    short* __restrict__ qb, short* __restrict__ kb)
{
  __shared__ float tile[64][65];
  const int tid = threadIdx.x;
  const int p0 = blockIdx.x * 64;
  const int ct = (blockIdx.y & 1) * 64;
  const int tens = blockIdx.y >> 1;
  const int b = blockIdx.z;
  const float* in = tens ? kw : qw;
  short* out = tens ? kb : qb;

  {
    int w = tid & 63, r = tid >> 6;
#pragma unroll
    for (int u = 0; u < 16; u += 4) {
      int cl = u + r;
      tile[cl][w] = in[((size_t)b * DD + ct + cl) * HW + p0 + w];
      tile[cl + 16][w] = in[((size_t)b * DD + ct + cl + 16) * HW + p0 + w];
      tile[cl + 32][w] = in[((size_t)b * DD + ct + cl + 32) * HW + p0 + w];
      tile[cl + 48][w] = in[((size_t)b * DD + ct + cl + 48) * HW + p0 + w];
    }
  }
  __syncthreads();
  {
    int p = tid >> 2, cq = (tid & 3) * 16;
    unsigned* dst = (unsigned*)(out + ((size_t)b * HW + p0 + p) * DD + ct + cq);
#pragma unroll
    for (int e = 0; e < 8; ++e)
      dst[e] = pk2(tile[cq + 2 * e][p], tile[cq + 2 * e + 1][p]);
  }
}

// ---------------- K2: pass1 MFMA partial sums: rl[j] += sum_{i in range} exp(s[i,j])
// i-range split x4 across blockIdx.y for occupancy (4 WG/CU); rl pre-zeroed.
__global__ __launch_bounds__(256) void k_lsum2(
    const short* __restrict__ qb, const short* __restrict__ kb,
    float* __restrict__ rl)
{
  __shared__ float lred[4][64];
  const int tid = threadIdx.x;
  const int w = tid >> 6;
  const int lane = tid & 63;
  const int t = lane & 15, q = lane >> 4;
  const int j0 = blockIdx.x * 64;
  const int ibeg = blockIdx.y * 1024;
  const int b = blockIdx.z;
  const short* qbb = qb + (size_t)b * HW * DD;
  const short* kbb = kb + (size_t)b * HW * DD;

  bf16x8 Bq[4][4];
#pragma unroll
  for (int nt = 0; nt < 4; ++nt)
#pragma unroll
    for (int kk = 0; kk < 4; ++kk)
      Bq[nt][kk] = *(const bf16x8*)(qbb + (size_t)(j0 + nt * 16 + t) * DD + kk * 32 + q * 8);

  float racc[4] = {0.f, 0.f, 0.f, 0.f};
  const f32x4 zf = {0.f, 0.f, 0.f, 0.f};

  for (int i = ibeg + w * 16; i < ibeg + 1024; i += 64) {
    bf16x8 Ak[4];
#pragma unroll
    for (int kk = 0; kk < 4; ++kk)
      Ak[kk] = *(const bf16x8*)(kbb + (size_t)(i + t) * DD + kk * 32 + q * 8);
#pragma unroll
    for (int nt = 0; nt < 4; ++nt) {
      f32x4 d = zf;
#pragma unroll
      for (int kk = 0; kk < 4; ++kk)
        d = __builtin_amdgcn_mfma_f32_16x16x32_bf16(Ak[kk], Bq[nt][kk], d, 0, 0, 0);
      racc[nt] += __expf(d[0]) + __expf(d[1]) + __expf(d[2]) + __expf(d[3]);
    }
  }
#pragma unroll
  for (int nt = 0; nt < 4; ++nt) {
    float r = racc[nt];
    r += __shfl_xor(r, 16);
    r += __shfl_xor(r, 32);
    if (q == 0) lred[w][nt * 16 + t] = r;
  }
  __syncthreads();
  if (tid < 64) {
    float sum = lred[0][tid] + lred[1][tid] + lred[2][tid] + lred[3][tid];
    atomicAdd(&rl[(size_t)b * HW + j0 + tid], sum);
  }
}

// ---------------- K2b: vs[c][j] = bf16( vw[c][j] / l_j )   (B,128,HW)
__global__ __launch_bounds__(256) void k_vs(
    const float* __restrict__ vw, const float* __restrict__ rl,
    short* __restrict__ vs)
{
  int id4 = (blockIdx.x * 256 + threadIdx.x) * 4;
  int j = id4 & (HW - 1);
  int b = id4 >> 19;
  float4 v = *(const float4*)&vw[id4];
  const float* rlb = rl + (size_t)b * HW + j;
  unsigned u0 = pk2(v.x / rlb[0], v.y / rlb[1]);
  unsigned u1 = pk2(v.z / rlb[2], v.w / rlb[3]);
  *(uint2*)(vs + id4) = make_uint2(u0, u1);
}

// ---------------- K3: pass2, LDS-staged: ao[i,:] += exp(S_i,jrange) @ Vs
// 32 i-rows/wave (128 i/WG): each Qs/Vss ds_read feeds 2 MFMAs (was 1),
// halving LDS reads per FLOP (R9's measured LDS-throughput bound).
// j-split 4 -> grid 512 = 2 WG/CU.
__global__ __launch_bounds__(256, 2) void k_attn2(
    const short* __restrict__ qb, const short* __restrict__ kb,
    const short* __restrict__ vs, float* __restrict__ ao)
{
  __shared__ __align__(16) short Qs[64 * 136];   // [j][c], stride 136 shorts
  __shared__ __align__(16) short Vss[128 * 72];  // [c][j], stride 72 shorts
  __shared__ __align__(16) short P[4][32][72];   // per-wave P tile
  const int tid = threadIdx.x;
  const int w = tid >> 6;
  const int lane = tid & 63;
  const int t = lane & 15, q = lane >> 4;
  const int b = blockIdx.z;
  const int i0 = blockIdx.x * 128 + w * 32;
  const int jbeg = blockIdx.y * 1024, jend = jbeg + 1024;
  const short* qbb = qb + (size_t)b * HW * DD;
  const short* kbb = kb + (size_t)b * HW * DD;
  const short* vsb = vs + (size_t)b * DD * HW;
  const f32x4 zf = {0.f, 0.f, 0.f, 0.f};

  // preload K fragments for wave's 32 i-rows: A[m=i][k=c]
  bf16x8 Ak[2][4];
#pragma unroll
  for (int mt = 0; mt < 2; ++mt)
#pragma unroll
    for (int kk = 0; kk < 4; ++kk)
      Ak[mt][kk] = *(const bf16x8*)(kbb + (size_t)(i0 + mt * 16 + t) * DD + kk * 32 + q * 8);

  f32x4 acc[2][8];
#pragma unroll
  for (int mt = 0; mt < 2; ++mt)
#pragma unroll
    for (int nt = 0; nt < 8; ++nt) acc[mt][nt] = zf;

  for (int j = jbeg; j < jend; j += 64) {
    __syncthreads();   // previous-step ds_reads complete before overwrite
    // stage Q tile: 1024 x 16B units
#pragma unroll
    for (int r = 0; r < 4; ++r) {
      int e = tid + (r << 8);
      int row = e >> 4, u = e & 15;
      *(bf16x8*)(Qs + row * 136 + u * 8) =
          *(const bf16x8*)(qbb + (size_t)(j + row) * DD + u * 8);
    }
    // stage Vs tile: 1024 x 16B units
#pragma unroll
    for (int r = 0; r < 4; ++r) {
      int e = tid + (r << 8);
      int c = e >> 3, u = e & 7;
      *(bf16x8*)(Vss + c * 72 + u * 8) =
          *(const bf16x8*)(vsb + (size_t)c * HW + j + u * 8);
    }
    __syncthreads();
    // --- S chunk: 32 i x 64 j
    f32x4 sv[2][4];
#pragma unroll
    for (int mt = 0; mt < 2; ++mt)
#pragma unroll
      for (int nt = 0; nt < 4; ++nt) sv[mt][nt] = zf;
#pragma unroll
    for (int nt = 0; nt < 4; ++nt)
#pragma unroll
      for (int kk = 0; kk < 4; ++kk) {
        bf16x8 bq = *(const bf16x8*)(Qs + (nt * 16 + t) * 136 + kk * 32 + q * 8);
        sv[0][nt] = __builtin_amdgcn_mfma_f32_16x16x32_bf16(Ak[0][kk], bq, sv[0][nt], 0, 0, 0);
        sv[1][nt] = __builtin_amdgcn_mfma_f32_16x16x32_bf16(Ak[1][kk], bq, sv[1][nt], 0, 0, 0);
      }
    // --- exp -> P (per-wave tile; same-wave RAW handled by lgkmcnt)
#pragma unroll
    for (int mt = 0; mt < 2; ++mt)
#pragma unroll
      for (int nt = 0; nt < 4; ++nt)
#pragma unroll
        for (int r = 0; r < 4; ++r)
          P[w][mt * 16 + q * 4 + r][nt * 16 + t] = f2b(__expf(sv[mt][nt][r]));
    // --- PV
    bf16x8 ap[2][2];
#pragma unroll
    for (int mt = 0; mt < 2; ++mt)
#pragma unroll
      for (int ks = 0; ks < 2; ++ks)
        ap[mt][ks] = *(const bf16x8*)&P[w][mt * 16 + t][ks * 32 + q * 8];
#pragma unroll
    for (int nt = 0; nt < 8; ++nt)
#pragma unroll
      for (int ks = 0; ks < 2; ++ks) {
        bf16x8 bv = *(const bf16x8*)(Vss + (nt * 16 + t) * 72 + ks * 32 + q * 8);
        acc[0][nt] = __builtin_amdgcn_mfma_f32_16x16x32_bf16(ap[0][ks], bv, acc[0][nt], 0, 0, 0);
        acc[1][nt] = __builtin_amdgcn_mfma_f32_16x16x32_bf16(ap[1][ks], bv, acc[1][nt], 0, 0, 0);
      }
  }
  // epilogue: atomic accumulate partials into ao (B,128,HW)
  float* aob = ao + (size_t)b * DD * HW;
#pragma unroll
  for (int mt = 0; mt < 2; ++mt)
#pragma unroll
    for (int nt = 0; nt < 8; ++nt)
#pragma unroll
      for (int r = 0; r < 4; ++r)
        atomicAdd(&aob[(size_t)(nt * 16 + t) * HW + i0 + mt * 16 + q * 4 + r],
                  acc[mt][nt][r]);
}

// ---------------- K4: y = tgt + gamma*(Wp@ao + bp) -> Xn interior, ch [0,256)
// Xn layout: (B, 66, 66, 768) NHWC bf16 with a zeroed guard ring.
__global__ __launch_bounds__(256) void k_proj(
    const float* __restrict__ ao, const float* __restrict__ tgt,
    const float* __restrict__ Wp, const float* __restrict__ bp,
    const float* __restrict__ gamma, short* __restrict__ Xn)
{
  __shared__ float Wt[32][132];
  __shared__ float Xs[32][68];
  __shared__ float T[64][133];
  const int tid = threadIdx.x;
  const int tx = tid & 15, ty = tid >> 4;
  const int p0 = blockIdx.x * 64;
  const int ro = blockIdx.y * 128;
  const int b = blockIdx.z;
  const float g0 = gamma[0];

  float acc[8][4];
#pragma unroll
  for (int i = 0; i < 8; ++i)
#pragma unroll
    for (int j = 0; j < 4; ++j) acc[i][j] = 0.f;

  for (int kk = 0; kk < DD; kk += 32) {
    __syncthreads();
#pragma unroll
    for (int u = 0; u < 4; ++u) {
      int e = tid + 256 * u;
      int c4 = (e & 7) * 4, r = e >> 3;
      float w[4]; ld4(w, &Wp[(ro + r) * DD + kk + c4]);
      Wt[c4 + 0][r] = w[0]; Wt[c4 + 1][r] = w[1];
      Wt[c4 + 2][r] = w[2]; Wt[c4 + 3][r] = w[3];
    }
#pragma unroll
    for (int u = 0; u < 2; ++u) {
      int e = tid + 256 * u;
      int p4 = (e & 15) * 4, c = e >> 4;
      *(float4*)&Xs[c][p4] = *(const float4*)&ao[(b * DD + kk + c) * HW + p0 + p4];
    }
    __syncthreads();
#pragma unroll 4
    for (int c = 0; c < 32; ++c) {
      float wa[8], xb[4];
      ld4(wa, &Wt[c][ty * 8]); ld4(wa + 4, &Wt[c][ty * 8 + 4]);
      ld4(xb, &Xs[c][tx * 4]);
#pragma unroll
      for (int rr = 0; rr < 8; ++rr)
#pragma unroll
        for (int pp = 0; pp < 4; ++pp) acc[rr][pp] += wa[rr] * xb[pp];
    }
  }
#pragma unroll
  for (int rr = 0; rr < 8; ++rr) {
    int r = ro + ty * 8 + rr;
    int idx = (b * CC + r) * HW + p0 + tx * 4;
    float4 t4 = *(const float4*)&tgt[idx];
    float bpv = bp[r];
    T[tx * 4 + 0][ty * 8 + rr] = t4.x + g0 * (acc[rr][0] + bpv);
    T[tx * 4 + 1][ty * 8 + rr] = t4.y + g0 * (acc[rr][1] + bpv);
    T[tx * 4 + 2][ty * 8 + rr] = t4.z + g0 * (acc[rr][2] + bpv);
    T[tx * 4 + 3][ty * 8 + rr] = t4.w + g0 * (acc[rr][3] + bpv);
  }
  __syncthreads();
  {
    int p = tid >> 2, cq = (tid & 3) * 32;
    int h = p0 >> 6;   // p0 multiple of 64 -> one h row per block
    unsigned* dst = (unsigned*)(Xn + ((((size_t)b * 66 + h + 1) * 66) + 1 + p) * 768 + ro + cq);
#pragma unroll
    for (int e = 0; e < 16; ++e)
      dst[e] = pk2(T[p][cq + 2 * e], T[p][cq + 2 * e + 1]);
  }
}

// ---------------- K4b: upsample prev into Xn interior, channels [256,768)
__global__ __launch_bounds__(256) void k_pack(
    const float* __restrict__ prev, short* __restrict__ Xn)
{
  __shared__ float tile[64][65];
  const int tid = threadIdx.x;
  const int h = blockIdx.x;
  const int ci0 = blockIdx.y * 64;
  const int b = blockIdx.z;

  {
    int w = tid & 63, r = tid >> 6;
    for (int cs = r; cs < 64; cs += 4)
      tile[cs][w] = prev[((size_t)b * 512 + ci0 + cs) * 1024 + (h >> 1) * 32 + (w >> 1)];
  }
  __syncthreads();
  {
    int ci = tid & 63, wq = tid >> 6;
    for (int ws2 = wq; ws2 < 64; ws2 += 4)
      Xn[((((size_t)b * 66 + h + 1) * 66) + 1 + ws2) * 768 + 256 + ci0 + ci] = f2b(tile[ci][ws2]);
  }
}

// ---------------- K4c: weight repack Wc(256,768,3,3) f32 -> Wb(256,9,768) bf16
__global__ __launch_bounds__(256) void k_wb(
    const float* __restrict__ Wc, short* __restrict__ Wb)
{
  int i = blockIdx.x * 256 + threadIdx.x;
  int o = i / 6912;
  int rem = i - o * 6912;
  int khw = rem / 768;
  int ci = rem - khw * 768;
  Wb[i] = f2b(Wc[(size_t)o * 6912 + ci * 9 + khw]);
}

// ---------------- K5: 3x3 conv as m97-style LDS-staged implicit GEMM.
__global__ __launch_bounds__(256, 2) void k_conv_mfma(
    const short* __restrict__ Xn,   // (B,66,66,768) bf16, guard ring zero
    const short* __restrict__ Wb,   // (256,9,768) bf16
    const float* __restrict__ bcw,
    short* __restrict__ cb)         // (B,256,4096) bf16
{
  __shared__ __align__(16) short smem[32400];  // A: [0,27648) ; X: [27648,32400)
  const int tid = threadIdx.x;
  const int wv = tid >> 6;
  const int lane = tid & 63;
  const int t = lane & 15, q = lane >> 4;
  const int h = blockIdx.x;
  const int m0blk = blockIdx.y * 128;
  const int b = blockIdx.z;

  const f32x4 zf = {0.f, 0.f, 0.f, 0.f};
  f32x4 acc[2][4];
#pragma unroll
  for (int mt = 0; mt < 2; ++mt)
#pragma unroll
    for (int nt = 0; nt < 4; ++nt) acc[mt][nt] = zf;

  for (int kh = 0; kh < 3; ++kh) {
    const short* wsrc = Wb + (size_t)m0blk * 6912 + (kh * 3) * 768;
    const short* xsrc = Xn + ((size_t)b * 66 + h + kh) * 66 * 768;
    for (int ci0 = 0; ci0 < 768; ci0 += 64) {
#pragma unroll
      for (int r = 0; r < 12; ++r) {
        int e = tid + (r << 8);
        int u = e & 7, ckw = e >> 3;
        int kw = ckw >> 7, cout = ckw & 127;
        bf16x8 v = *(const bf16x8*)(wsrc + (size_t)cout * 6912 + kw * 768 + ci0 + u * 8);
        *(bf16x8*)(smem + ckw * 72 + u * 8) = v;
      }
#pragma unroll
      for (int r = 0; r < 3; ++r) {
        int e = tid + (r << 8);
        if (e < 528) {
          int u = e & 7, px = e >> 3;
          bf16x8 v = *(const bf16x8*)(xsrc + (size_t)px * 768 + ci0 + u * 8);
          *(bf16x8*)(smem + 27648 + px * 72 + u * 8) = v;
        }
      }
      __syncthreads();
#pragma unroll
      for (int kw = 0; kw < 3; ++kw) {
        bf16x8 af[2][2], bfr[4][2];
#pragma unroll
        for (int kk = 0; kk < 2; ++kk) {
#pragma unroll
          for (int mt = 0; mt < 2; ++mt)
            af[mt][kk] = *(const bf16x8*)(smem +
                (kw * 128 + wv * 32 + mt * 16 + t) * 72 + kk * 32 + q * 8);
#pragma unroll
          for (int nt = 0; nt < 4; ++nt)
            bfr[nt][kk] = *(const bf16x8*)(smem + 27648 +
                (nt * 16 + t + kw) * 72 + kk * 32 + q * 8);
        }
#pragma unroll
        for (int kk = 0; kk < 2; ++kk)
#pragma unroll
          for (int mt = 0; mt < 2; ++mt)
#pragma unroll
            for (int nt = 0; nt < 4; ++nt)
              acc[mt][nt] = __builtin_amdgcn_mfma_f32_16x16x32_bf16(
                  af[mt][kk], bfr[nt][kk], acc[mt][nt], 0, 0, 0);
      }
      __syncthreads();
    }
  }
#pragma unroll
  for (int mt = 0; mt < 2; ++mt) {
    int om = m0blk + wv * 32 + mt * 16 + q * 4;
#pragma unroll
    for (int r = 0; r < 4; ++r) {
      float bias = bcw[om + r];
      short* orow = cb + ((size_t)b * CC + om + r) * HW + h * 64;
#pragma unroll
      for (int nt = 0; nt < 4; ++nt)
        orow[nt * 16 + t] = f2b(acc[mt][nt][r] + bias);
    }
  }
}

// ---------------- K6: InstanceNorm (biased var, eps=1e-5) + ReLU; bf16 in, f32 out
__global__ __launch_bounds__(256) void k_inorm(
    const short* __restrict__ cb, float* __restrict__ out)
{
  __shared__ float buf[4096];
  __shared__ float red[8];
  const int tid = threadIdx.x;
  const int ch = blockIdx.x;
  const short* srcp = cb + (size_t)ch * HW;

  float s = 0.f, sq = 0.f;
#pragma unroll
  for (int u = 0; u < 2; ++u) {
    int sidx = u * 2048 + tid * 8;
    uint4 pk = *(const uint4*)(srcp + sidx);
    float f[8];
    f[0] = __uint_as_float(pk.x << 16); f[1] = __uint_as_float(pk.x & 0xffff0000u);
    f[2] = __uint_as_float(pk.y << 16); f[3] = __uint_as_float(pk.y & 0xffff0000u);
    f[4] = __uint_as_float(pk.z << 16); f[5] = __uint_as_float(pk.z & 0xffff0000u);
    f[6] = __uint_as_float(pk.w << 16); f[7] = __uint_as_float(pk.w & 0xffff0000u);
#pragma unroll
    for (int e = 0; e < 8; ++e) {
      buf[sidx + e] = f[e];
      s += f[e];
      sq += f[e] * f[e];
    }
  }
#pragma unroll
  for (int m = 32; m >= 1; m >>= 1) {
    s  += __shfl_xor(s, m, 64);
    sq += __shfl_xor(sq, m, 64);
  }
  if ((tid & 63) == 0) { red[tid >> 6] = s; red[4 + (tid >> 6)] = sq; }
  __syncthreads();
  if (tid == 0) {
    float S = red[0] + red[1] + red[2] + red[3];
    float Q = red[4] + red[5] + red[6] + red[7];
    float mean = S * (1.f / HW);
    float var = Q * (1.f / HW) - mean * mean;
    red[0] = mean;
    red[1] = rsqrtf(var + 1e-5f);
  }
  __syncthreads();
  const float mean = red[0], rs = red[1];
#pragma unroll
  for (int u = 0; u < 4; ++u) {
    int idx = u * 1024 + tid * 4;
    float4 v = *(const float4*)&buf[idx];
    float4 o4 = make_float4(fmaxf((v.x - mean) * rs, 0.f),
                            fmaxf((v.y - mean) * rs, 0.f),
                            fmaxf((v.z - mean) * rs, 0.f),
                            fmaxf((v.w - mean) * rs, 0.f));
    *(float4*)&out[(size_t)ch * HW + idx] = o4;
  }
}

extern "C" void kernel_launch(void* const* d_in, const int* in_sizes, int n_in,
                              void* d_out, int out_size, void* d_ws, size_t ws_size,
                              hipStream_t stream) {
  const float* src  = (const float*)d_in[0];
  const float* tgt  = (const float*)d_in[1];
  const float* prev = (const float*)d_in[2];
  const float* Wq = (const float*)d_in[3];  const float* bq = (const float*)d_in[4];
  const float* Wk = (const float*)d_in[5];  const float* bk = (const float*)d_in[6];
  const float* Wv = (const float*)d_in[7];  const float* bv = (const float*)d_in[8];
  const float* Wp = (const float*)d_in[9];  const float* bp = (const float*)d_in[10];
  const float* gamma = (const float*)d_in[11];
  const float* Wc = (const float*)d_in[12]; const float* bcw = (const float*)d_in[13];

  float* ws = (float*)d_ws;
  // float-unit offsets; lifetimes:
  float* qw = ws;                         // [0, 2097152)        dead after k_qkb
  float* kw = ws + 2097152;               // [2097152, 4194304)  dead after k_qkb
  float* vw = ws + 4194304;               // [4194304, 6291456)  dead after k_vs
  float* rl = ws + 6291456;               // [6291456, 6307840)  dead after k_vs
  short* qb = (short*)(ws + 6307840);     // [6307840, 7356416)  dead after k_attn2
  short* kb = (short*)(ws + 7356416);     // [7356416, 8404992)  dead after k_attn2
  short* vs = (short*)(ws + 8404992);     // [8404992, 9453568)  dead after k_attn2
  float* ao = ws;                         // [0, 2097152)  over qw; zeroed below
  short* Xn = (short*)(ws + 2097152);     // [2097152, 8787968)  (B,66,66,768) over kw/vw/rl/qb/kb/vs
  short* cb = (short*)(ws);               // [0, 2097152)  over ao (ao dead after k_proj)
  short* Wb = (short*)(ws + 9453568);     // [9453568, 10338304)
  // high-water: 10,338,304 floats = 41.4 MB

  k_qkv  <<<dim3(64, 3, BB), 256, 0, stream>>>(src, tgt, Wq, bq, Wk, bk, Wv, bv, qw, kw, vw);
  k_qkb  <<<dim3(64, 4, BB), 256, 0, stream>>>(qw, kw, qb, kb);
  hipMemsetAsync(rl, 0, (size_t)BB * HW * 4, stream);
  k_lsum2<<<dim3(64, 4, BB), 256, 0, stream>>>(qb, kb, rl);
  k_vs   <<<dim3(2048),      256, 0, stream>>>(vw, rl, vs);
  hipMemsetAsync(ao, 0, (size_t)2097152 * 4, stream);
  k_attn2<<<dim3(32, 4, BB), 256, 0, stream>>>(qb, kb, vs, ao);
  // Xn overlaps qb/kb/vs -> zero it only after k_attn2 (also zeroes guard ring)
  hipMemsetAsync(Xn, 0, (size_t)BB * 66 * 66 * 768 * 2, stream);
  k_proj <<<dim3(64, 2, BB), 256, 0, stream>>>(ao, tgt, Wp, bp, gamma, Xn);
  k_pack <<<dim3(64, 8, BB), 256, 0, stream>>>(prev, Xn);
  k_wb   <<<dim3(6912),      256, 0, stream>>>(Wc, Wb);
  k_conv_mfma<<<dim3(64, 2, BB), 256, 0, stream>>>(Xn, Wb, bcw, cb);
  k_inorm<<<dim3(1024),      256, 0, stream>>>(cb, (float*)d_out);
}

// Round 11
// 429.511 us; speedup vs baseline: 1.1915x; 1.1915x over previous
//
#include <hip/hip_runtime.h>
#include <hip/hip_bf16.h>

#define BB 4
#define CC 256
#define HW 4096
#define DD 128

typedef __attribute__((ext_vector_type(8))) short bf16x8;
typedef __attribute__((ext_vector_type(4))) float f32x4;

static __device__ __forceinline__ void ld4(float* dst, const float* src) {
  float4 t = *(const float4*)src;
  dst[0] = t.x; dst[1] = t.y; dst[2] = t.z; dst[3] = t.w;
}

// float -> bf16 (RNE) raw bits
static __device__ __forceinline__ short f2b(float f) {
  unsigned u = __float_as_uint(f);
  u += 0x7fffu + ((u >> 16) & 1u);
  return (short)(u >> 16);
}
static __device__ __forceinline__ unsigned pk2(float lo, float hi) {
  return (unsigned)(unsigned short)f2b(lo) | ((unsigned)(unsigned short)f2b(hi) << 16);
}

// ---------------- K1: q/k/v 1x1 conv as LDS-staged bf16 MFMA.
// Per (pxtile, which, b): GEMM W(128x256) @ X(256x64px).
// Outputs: q,k -> (B,HW,128) bf16 (pre-transposed for attention);
//          v   -> (B,128,HW) bf16.
__global__ __launch_bounds__(256) void k_qkv_mfma(
    const float* __restrict__ src, const float* __restrict__ tgt,
    const float* __restrict__ Wq, const float* __restrict__ bq,
    const float* __restrict__ Wk, const float* __restrict__ bk,
    const float* __restrict__ Wv, const float* __restrict__ bv,
    short* __restrict__ qb, short* __restrict__ kb, short* __restrict__ vb)
{
  __shared__ __align__(16) short Wt[128 * 40];  // [ch][c], stride 40 (2-way free)
  __shared__ __align__(16) short Xt[64 * 40];   // [px][c]
  __shared__ __align__(16) short T[9216];       // epilogue tile
  const int tid = threadIdx.x;
  const int wv = tid >> 6;
  const int lane = tid & 63;
  const int t = lane & 15, q = lane >> 4;
  const int px0 = blockIdx.x * 64;
  const int which = blockIdx.y;
  const int b = blockIdx.z;
  const float* X    = (which == 0) ? src : tgt;
  const float* Wm   = (which == 0) ? Wq : (which == 1) ? Wk : Wv;
  const float* bias = (which == 0) ? bq : (which == 1) ? bk : bv;

  const f32x4 zf = {0.f, 0.f, 0.f, 0.f};
  f32x4 acc[2][4];
#pragma unroll
  for (int mt = 0; mt < 2; ++mt)
#pragma unroll
    for (int nt = 0; nt < 4; ++nt) acc[mt][nt] = zf;

  for (int kk = 0; kk < CC; kk += 32) {
    __syncthreads();
    // stage W tile: 128 ch x 32 c (f32 -> bf16)
#pragma unroll
    for (int u = 0; u < 4; ++u) {
      int e = tid + (u << 8);
      int row = e >> 3, cq = (e & 7) * 4;
      float4 w4 = *(const float4*)&Wm[row * CC + kk + cq];
      unsigned* dst = (unsigned*)(Wt + row * 40 + cq);
      dst[0] = pk2(w4.x, w4.y);
      dst[1] = pk2(w4.z, w4.w);
    }
    // stage X tile transposed: 32 c x 64 px -> Xt[px][c]
#pragma unroll
    for (int u = 0; u < 2; ++u) {
      int e = tid + (u << 8);
      int c = e >> 4, p4 = (e & 15) * 4;
      float4 xv = *(const float4*)&X[((size_t)b * CC + kk + c) * HW + px0 + p4];
      Xt[(p4 + 0) * 40 + c] = f2b(xv.x);
      Xt[(p4 + 1) * 40 + c] = f2b(xv.y);
      Xt[(p4 + 2) * 40 + c] = f2b(xv.z);
      Xt[(p4 + 3) * 40 + c] = f2b(xv.w);
    }
    __syncthreads();
    bf16x8 af[2], bfr[4];
#pragma unroll
    for (int mt = 0; mt < 2; ++mt)
      af[mt] = *(const bf16x8*)(Wt + (wv * 32 + mt * 16 + t) * 40 + q * 8);
#pragma unroll
    for (int nt = 0; nt < 4; ++nt)
      bfr[nt] = *(const bf16x8*)(Xt + (nt * 16 + t) * 40 + q * 8);
#pragma unroll
    for (int mt = 0; mt < 2; ++mt)
#pragma unroll
      for (int nt = 0; nt < 4; ++nt)
        acc[mt][nt] = __builtin_amdgcn_mfma_f32_16x16x32_bf16(
            af[mt], bfr[nt], acc[mt][nt], 0, 0, 0);
  }
  __syncthreads();
  // D mapping (verified idiom): ch = wv*32 + mt*16 + q*4 + r, px = nt*16 + t
  if (which < 2) {
    // T[px][ch], stride 136 -> coalesced (B,HW,128) store
#pragma unroll
    for (int mt = 0; mt < 2; ++mt) {
      int chb = wv * 32 + mt * 16 + q * 4;
#pragma unroll
      for (int r = 0; r < 4; ++r) {
        float bv_ = bias[chb + r];
#pragma unroll
        for (int nt = 0; nt < 4; ++nt)
          T[(nt * 16 + t) * 136 + chb + r] = f2b(acc[mt][nt][r] + bv_);
      }
    }
    __syncthreads();
    short* out = (which == 0) ? qb : kb;
    int p = tid >> 2, cq = (tid & 3) * 32;
    short* gdst = out + ((size_t)b * HW + px0 + p) * DD + cq;
#pragma unroll
    for (int e2 = 0; e2 < 4; ++e2)
      *(uint4*)(gdst + e2 * 8) = *(const uint4*)(T + p * 136 + cq + e2 * 8);
  } else {
    // T[ch][px], stride 72 -> coalesced (B,128,HW) store
#pragma unroll
    for (int mt = 0; mt < 2; ++mt) {
      int chb = wv * 32 + mt * 16 + q * 4;
#pragma unroll
      for (int r = 0; r < 4; ++r) {
        float bv_ = bias[chb + r];
#pragma unroll
        for (int nt = 0; nt < 4; ++nt)
          T[(chb + r) * 72 + nt * 16 + t] = f2b(acc[mt][nt][r] + bv_);
      }
    }
    __syncthreads();
    int ch = tid >> 1, pq = (tid & 1) * 32;
    short* gdst = vb + ((size_t)b * DD + ch) * HW + px0 + pq;
#pragma unroll
    for (int e2 = 0; e2 < 4; ++e2)
      *(uint4*)(gdst + e2 * 8) = *(const uint4*)(T + ch * 72 + pq + e2 * 8);
  }
}

// ---------------- K2: pass1 MFMA partial sums: rl[j] += sum_{i in range} exp(s[i,j])
// i-range split x4 across blockIdx.y for occupancy; rl pre-zeroed.
__global__ __launch_bounds__(256) void k_lsum2(
    const short* __restrict__ qb, const short* __restrict__ kb,
    float* __restrict__ rl)
{
  __shared__ float lred[4][64];
  const int tid = threadIdx.x;
  const int w = tid >> 6;
  const int lane = tid & 63;
  const int t = lane & 15, q = lane >> 4;
  const int j0 = blockIdx.x * 64;
  const int ibeg = blockIdx.y * 1024;
  const int b = blockIdx.z;
  const short* qbb = qb + (size_t)b * HW * DD;
  const short* kbb = kb + (size_t)b * HW * DD;

  bf16x8 Bq[4][4];
#pragma unroll
  for (int nt = 0; nt < 4; ++nt)
#pragma unroll
    for (int kk = 0; kk < 4; ++kk)
      Bq[nt][kk] = *(const bf16x8*)(qbb + (size_t)(j0 + nt * 16 + t) * DD + kk * 32 + q * 8);

  float racc[4] = {0.f, 0.f, 0.f, 0.f};
  const f32x4 zf = {0.f, 0.f, 0.f, 0.f};

  for (int i = ibeg + w * 16; i < ibeg + 1024; i += 64) {
    bf16x8 Ak[4];
#pragma unroll
    for (int kk = 0; kk < 4; ++kk)
      Ak[kk] = *(const bf16x8*)(kbb + (size_t)(i + t) * DD + kk * 32 + q * 8);
#pragma unroll
    for (int nt = 0; nt < 4; ++nt) {
      f32x4 d = zf;
#pragma unroll
      for (int kk = 0; kk < 4; ++kk)
        d = __builtin_amdgcn_mfma_f32_16x16x32_bf16(Ak[kk], Bq[nt][kk], d, 0, 0, 0);
      racc[nt] += __expf(d[0]) + __expf(d[1]) + __expf(d[2]) + __expf(d[3]);
    }
  }
#pragma unroll
  for (int nt = 0; nt < 4; ++nt) {
    float r = racc[nt];
    r += __shfl_xor(r, 16);
    r += __shfl_xor(r, 32);
    if (q == 0) lred[w][nt * 16 + t] = r;
  }
  __syncthreads();
  if (tid < 64) {
    float sum = lred[0][tid] + lred[1][tid] + lred[2][tid] + lred[3][tid];
    atomicAdd(&rl[(size_t)b * HW + j0 + tid], sum);
  }
}

// ---------------- K2b: vs[c][j] = bf16( vb[c][j] / l_j )   (B,128,HW)
__global__ __launch_bounds__(256) void k_vs(
    const short* __restrict__ vb, const float* __restrict__ rl,
    short* __restrict__ vs)
{
  int id4 = (blockIdx.x * 256 + threadIdx.x) * 4;
  int j = id4 & (HW - 1);
  int b = id4 >> 19;
  uint2 pv = *(const uint2*)(vb + id4);
  float f0 = __uint_as_float(pv.x << 16);
  float f1 = __uint_as_float(pv.x & 0xffff0000u);
  float f2 = __uint_as_float(pv.y << 16);
  float f3 = __uint_as_float(pv.y & 0xffff0000u);
  const float* rlb = rl + (size_t)b * HW + j;
  unsigned u0 = pk2(f0 / rlb[0], f1 / rlb[1]);
  unsigned u1 = pk2(f2 / rlb[2], f3 / rlb[3]);
  *(uint2*)(vs + id4) = make_uint2(u0, u1);
}

// ---------------- K3: pass2, LDS-staged (R9 known-good): ao[i,:] += exp(S) @ Vs
__global__ __launch_bounds__(256, 2) void k_attn2(
    const short* __restrict__ qb, const short* __restrict__ kb,
    const short* __restrict__ vs, float* __restrict__ ao)
{
  __shared__ __align__(16) short Qs[64 * 136];   // [j][c], stride 136 shorts
  __shared__ __align__(16) short Vss[128 * 72];  // [c][j], stride 72 shorts
  __shared__ __align__(16) short P[4][16][72];   // per-wave P tile
  const int tid = threadIdx.x;
  const int w = tid >> 6;
  const int lane = tid & 63;
  const int t = lane & 15, q = lane >> 4;
  const int b = blockIdx.z;
  const int i0 = blockIdx.x * 64 + w * 16;
  const int jbeg = blockIdx.y * 2048, jend = jbeg + 2048;
  const short* qbb = qb + (size_t)b * HW * DD;
  const short* kbb = kb + (size_t)b * HW * DD;
  const short* vsb = vs + (size_t)b * DD * HW;
  const f32x4 zf = {0.f, 0.f, 0.f, 0.f};

  bf16x8 Ak[4];
#pragma unroll
  for (int kk = 0; kk < 4; ++kk)
    Ak[kk] = *(const bf16x8*)(kbb + (size_t)(i0 + t) * DD + kk * 32 + q * 8);

  f32x4 acc[8];
#pragma unroll
  for (int nt = 0; nt < 8; ++nt) acc[nt] = zf;

  for (int j = jbeg; j < jend; j += 64) {
    __syncthreads();
#pragma unroll
    for (int r = 0; r < 4; ++r) {
      int e = tid + (r << 8);
      int row = e >> 4, u = e & 15;
      *(bf16x8*)(Qs + row * 136 + u * 8) =
          *(const bf16x8*)(qbb + (size_t)(j + row) * DD + u * 8);
    }
#pragma unroll
    for (int r = 0; r < 4; ++r) {
      int e = tid + (r << 8);
      int c = e >> 3, u = e & 7;
      *(bf16x8*)(Vss + c * 72 + u * 8) =
          *(const bf16x8*)(vsb + (size_t)c * HW + j + u * 8);
    }
    __syncthreads();
    f32x4 sv[4];
#pragma unroll
    for (int nt = 0; nt < 4; ++nt) sv[nt] = zf;
#pragma unroll
    for (int nt = 0; nt < 4; ++nt)
#pragma unroll
      for (int kk = 0; kk < 4; ++kk) {
        bf16x8 bq = *(const bf16x8*)(Qs + (nt * 16 + t) * 136 + kk * 32 + q * 8);
        sv[nt] = __builtin_amdgcn_mfma_f32_16x16x32_bf16(Ak[kk], bq, sv[nt], 0, 0, 0);
      }
#pragma unroll
    for (int nt = 0; nt < 4; ++nt)
#pragma unroll
      for (int r = 0; r < 4; ++r)
        P[w][q * 4 + r][nt * 16 + t] = f2b(__expf(sv[nt][r]));
    bf16x8 ap[2];
#pragma unroll
    for (int ks = 0; ks < 2; ++ks)
      ap[ks] = *(const bf16x8*)&P[w][t][ks * 32 + q * 8];
#pragma unroll
    for (int nt = 0; nt < 8; ++nt)
#pragma unroll
      for (int ks = 0; ks < 2; ++ks) {
        bf16x8 bv = *(const bf16x8*)(Vss + (nt * 16 + t) * 72 + ks * 32 + q * 8);
        acc[nt] = __builtin_amdgcn_mfma_f32_16x16x32_bf16(ap[ks], bv, acc[nt], 0, 0, 0);
      }
  }
  float* aob = ao + (size_t)b * DD * HW;
#pragma unroll
  for (int nt = 0; nt < 8; ++nt)
#pragma unroll
    for (int r = 0; r < 4; ++r)
      atomicAdd(&aob[(size_t)(nt * 16 + t) * HW + i0 + q * 4 + r], acc[nt][r]);
}

// ---------------- K4: y = tgt + gamma*(Wp@ao + bp) -> Xn interior, ch [0,256)
// Xn layout: (B, 66, 66, 768) NHWC bf16 with a zeroed guard ring.
__global__ __launch_bounds__(256) void k_proj(
    const float* __restrict__ ao, const float* __restrict__ tgt,
    const float* __restrict__ Wp, const float* __restrict__ bp,
    const float* __restrict__ gamma, short* __restrict__ Xn)
{
  __shared__ float Wt[32][132];
  __shared__ float Xs[32][68];
  __shared__ float T[64][133];
  const int tid = threadIdx.x;
  const int tx = tid & 15, ty = tid >> 4;
  const int p0 = blockIdx.x * 64;
  const int ro = blockIdx.y * 128;
  const int b = blockIdx.z;
  const float g0 = gamma[0];

  float acc[8][4];
#pragma unroll
  for (int i = 0; i < 8; ++i)
#pragma unroll
    for (int j = 0; j < 4; ++j) acc[i][j] = 0.f;

  for (int kk = 0; kk < DD; kk += 32) {
    __syncthreads();
#pragma unroll
    for (int u = 0; u < 4; ++u) {
      int e = tid + 256 * u;
      int c4 = (e & 7) * 4, r = e >> 3;
      float w[4]; ld4(w, &Wp[(ro + r) * DD + kk + c4]);
      Wt[c4 + 0][r] = w[0]; Wt[c4 + 1][r] = w[1];
      Wt[c4 + 2][r] = w[2]; Wt[c4 + 3][r] = w[3];
    }
#pragma unroll
    for (int u = 0; u < 2; ++u) {
      int e = tid + 256 * u;
      int p4 = (e & 15) * 4, c = e >> 4;
      *(float4*)&Xs[c][p4] = *(const float4*)&ao[(b * DD + kk + c) * HW + p0 + p4];
    }
    __syncthreads();
#pragma unroll 4
    for (int c = 0; c < 32; ++c) {
      float wa[8], xb[4];
      ld4(wa, &Wt[c][ty * 8]); ld4(wa + 4, &Wt[c][ty * 8 + 4]);
      ld4(xb, &Xs[c][tx * 4]);
#pragma unroll
      for (int rr = 0; rr < 8; ++rr)
#pragma unroll
        for (int pp = 0; pp < 4; ++pp) acc[rr][pp] += wa[rr] * xb[pp];
    }
  }
#pragma unroll
  for (int rr = 0; rr < 8; ++rr) {
    int r = ro + ty * 8 + rr;
    int idx = (b * CC + r) * HW + p0 + tx * 4;
    float4 t4 = *(const float4*)&tgt[idx];
    float bpv = bp[r];
    T[tx * 4 + 0][ty * 8 + rr] = t4.x + g0 * (acc[rr][0] + bpv);
    T[tx * 4 + 1][ty * 8 + rr] = t4.y + g0 * (acc[rr][1] + bpv);
    T[tx * 4 + 2][ty * 8 + rr] = t4.z + g0 * (acc[rr][2] + bpv);
    T[tx * 4 + 3][ty * 8 + rr] = t4.w + g0 * (acc[rr][3] + bpv);
  }
  __syncthreads();
  {
    int p = tid >> 2, cq = (tid & 3) * 32;
    int h = p0 >> 6;
    unsigned* dst = (unsigned*)(Xn + ((((size_t)b * 66 + h + 1) * 66) + 1 + p) * 768 + ro + cq);
#pragma unroll
    for (int e = 0; e < 16; ++e)
      dst[e] = pk2(T[p][cq + 2 * e], T[p][cq + 2 * e + 1]);
  }
}

// ---------------- K4b: upsample prev into Xn interior, channels [256,768)
__global__ __launch_bounds__(256) void k_pack(
    const float* __restrict__ prev, short* __restrict__ Xn)
{
  __shared__ float tile[64][65];
  const int tid = threadIdx.x;
  const int h = blockIdx.x;
  const int ci0 = blockIdx.y * 64;
  const int b = blockIdx.z;

  {
    int w = tid & 63, r = tid >> 6;
    for (int cs = r; cs < 64; cs += 4)
      tile[cs][w] = prev[((size_t)b * 512 + ci0 + cs) * 1024 + (h >> 1) * 32 + (w >> 1)];
  }
  __syncthreads();
  {
    int ci = tid & 63, wq = tid >> 6;
    for (int ws2 = wq; ws2 < 64; ws2 += 4)
      Xn[((((size_t)b * 66 + h + 1) * 66) + 1 + ws2) * 768 + 256 + ci0 + ci] = f2b(tile[ci][ws2]);
  }
}

// ---------------- K4c: weight repack Wc(256,768,3,3) f32 -> Wb(256,9,768) bf16
__global__ __launch_bounds__(256) void k_wb(
    const float* __restrict__ Wc, short* __restrict__ Wb)
{
  int i = blockIdx.x * 256 + threadIdx.x;
  int o = i / 6912;
  int rem = i - o * 6912;
  int khw = rem / 768;
  int ci = rem - khw * 768;
  Wb[i] = f2b(Wc[(size_t)o * 6912 + ci * 9 + khw]);
}

// ---------------- K5: 3x3 conv as m97-style LDS-staged implicit GEMM.
__global__ __launch_bounds__(256, 2) void k_conv_mfma(
    const short* __restrict__ Xn,   // (B,66,66,768) bf16, guard ring zero
    const short* __restrict__ Wb,   // (256,9,768) bf16
    const float* __restrict__ bcw,
    short* __restrict__ cb)         // (B,256,4096) bf16
{
  __shared__ __align__(16) short smem[32400];  // A: [0,27648) ; X: [27648,32400)
  const int tid = threadIdx.x;
  const int wv = tid >> 6;
  const int lane = tid & 63;
  const int t = lane & 15, q = lane >> 4;
  const int h = blockIdx.x;
  const int m0blk = blockIdx.y * 128;
  const int b = blockIdx.z;

  const f32x4 zf = {0.f, 0.f, 0.f, 0.f};
  f32x4 acc[2][4];
#pragma unroll
  for (int mt = 0; mt < 2; ++mt)
#pragma unroll
    for (int nt = 0; nt < 4; ++nt) acc[mt][nt] = zf;

  for (int kh = 0; kh < 3; ++kh) {
    const short* wsrc = Wb + (size_t)m0blk * 6912 + (kh * 3) * 768;
    const short* xsrc = Xn + ((size_t)b * 66 + h + kh) * 66 * 768;
    for (int ci0 = 0; ci0 < 768; ci0 += 64) {
#pragma unroll
      for (int r = 0; r < 12; ++r) {
        int e = tid + (r << 8);
        int u = e & 7, ckw = e >> 3;
        int kw = ckw >> 7, cout = ckw & 127;
        bf16x8 v = *(const bf16x8*)(wsrc + (size_t)cout * 6912 + kw * 768 + ci0 + u * 8);
        *(bf16x8*)(smem + ckw * 72 + u * 8) = v;
      }
#pragma unroll
      for (int r = 0; r < 3; ++r) {
        int e = tid + (r << 8);
        if (e < 528) {
          int u = e & 7, px = e >> 3;
          bf16x8 v = *(const bf16x8*)(xsrc + (size_t)px * 768 + ci0 + u * 8);
          *(bf16x8*)(smem + 27648 + px * 72 + u * 8) = v;
        }
      }
      __syncthreads();
#pragma unroll
      for (int kw = 0; kw < 3; ++kw) {
        bf16x8 af[2][2], bfr[4][2];
#pragma unroll
        for (int kk = 0; kk < 2; ++kk) {
#pragma unroll
          for (int mt = 0; mt < 2; ++mt)
            af[mt][kk] = *(const bf16x8*)(smem +
                (kw * 128 + wv * 32 + mt * 16 + t) * 72 + kk * 32 + q * 8);
#pragma unroll
          for (int nt = 0; nt < 4; ++nt)
            bfr[nt][kk] = *(const bf16x8*)(smem + 27648 +
                (nt * 16 + t + kw) * 72 + kk * 32 + q * 8);
        }
#pragma unroll
        for (int kk = 0; kk < 2; ++kk)
#pragma unroll
          for (int mt = 0; mt < 2; ++mt)
#pragma unroll
            for (int nt = 0; nt < 4; ++nt)
              acc[mt][nt] = __builtin_amdgcn_mfma_f32_16x16x32_bf16(
                  af[mt][kk], bfr[nt][kk], acc[mt][nt], 0, 0, 0);
      }
      __syncthreads();
    }
  }
#pragma unroll
  for (int mt = 0; mt < 2; ++mt) {
    int om = m0blk + wv * 32 + mt * 16 + q * 4;
#pragma unroll
    for (int r = 0; r < 4; ++r) {
      float bias = bcw[om + r];
      short* orow = cb + ((size_t)b * CC + om + r) * HW + h * 64;
#pragma unroll
      for (int nt = 0; nt < 4; ++nt)
        orow[nt * 16 + t] = f2b(acc[mt][nt][r] + bias);
    }
  }
}

// ---------------- K6: InstanceNorm (biased var, eps=1e-5) + ReLU; bf16 in, f32 out
__global__ __launch_bounds__(256) void k_inorm(
    const short* __restrict__ cb, float* __restrict__ out)
{
  __shared__ float buf[4096];
  __shared__ float red[8];
  const int tid = threadIdx.x;
  const int ch = blockIdx.x;
  const short* srcp = cb + (size_t)ch * HW;

  float s = 0.f, sq = 0.f;
#pragma unroll
  for (int u = 0; u < 2; ++u) {
    int sidx = u * 2048 + tid * 8;
    uint4 pk = *(const uint4*)(srcp + sidx);
    float f[8];
    f[0] = __uint_as_float(pk.x << 16); f[1] = __uint_as_float(pk.x & 0xffff0000u);
    f[2] = __uint_as_float(pk.y << 16); f[3] = __uint_as_float(pk.y & 0xffff0000u);
    f[4] = __uint_as_float(pk.z << 16); f[5] = __uint_as_float(pk.z & 0xffff0000u);
    f[6] = __uint_as_float(pk.w << 16); f[7] = __uint_as_float(pk.w & 0xffff0000u);
#pragma unroll
    for (int e = 0; e < 8; ++e) {
      buf[sidx + e] = f[e];
      s += f[e];
      sq += f[e] * f[e];
    }
  }
#pragma unroll
  for (int m = 32; m >= 1; m >>= 1) {
    s  += __shfl_xor(s, m, 64);
    sq += __shfl_xor(sq, m, 64);
  }
  if ((tid & 63) == 0) { red[tid >> 6] = s; red[4 + (tid >> 6)] = sq; }
  __syncthreads();
  if (tid == 0) {
    float S = red[0] + red[1] + red[2] + red[3];
    float Q = red[4] + red[5] + red[6] + red[7];
    float mean = S * (1.f / HW);
    float var = Q * (1.f / HW) - mean * mean;
    red[0] = mean;
    red[1] = rsqrtf(var + 1e-5f);
  }
  __syncthreads();
  const float mean = red[0], rs = red[1];
#pragma unroll
  for (int u = 0; u < 4; ++u) {
    int idx = u * 1024 + tid * 4;
    float4 v = *(const float4*)&buf[idx];
    float4 o4 = make_float4(fmaxf((v.x - mean) * rs, 0.f),
                            fmaxf((v.y - mean) * rs, 0.f),
                            fmaxf((v.z - mean) * rs, 0.f),
                            fmaxf((v.w - mean) * rs, 0.f));
    *(float4*)&out[(size_t)ch * HW + idx] = o4;
  }
}

extern "C" void kernel_launch(void* const* d_in, const int* in_sizes, int n_in,
                              void* d_out, int out_size, void* d_ws, size_t ws_size,
                              hipStream_t stream) {
  const float* src  = (const float*)d_in[0];
  const float* tgt  = (const float*)d_in[1];
  const float* prev = (const float*)d_in[2];
  const float* Wq = (const float*)d_in[3];  const float* bq = (const float*)d_in[4];
  const float* Wk = (const float*)d_in[5];  const float* bk = (const float*)d_in[6];
  const float* Wv = (const float*)d_in[7];  const float* bv = (const float*)d_in[8];
  const float* Wp = (const float*)d_in[9];  const float* bp = (const float*)d_in[10];
  const float* gamma = (const float*)d_in[11];
  const float* Wc = (const float*)d_in[12]; const float* bcw = (const float*)d_in[13];

  float* ws = (float*)d_ws;
  // float-unit offsets; lifetimes:
  short* qb = (short*)ws;                 // [0, 1048576)        dead after k_attn2
  short* kb = (short*)(ws + 1048576);     // [1048576, 2097152)  dead after k_attn2
  short* vb = (short*)(ws + 2097152);     // [2097152, 3145728)  dead after k_vs
  float* rl = ws + 3145728;               // [3145728, 3162112)  dead after k_vs
  short* vs = (short*)(ws + 3162112);     // [3162112, 4210688)  dead after k_attn2
  short* Xn = (short*)ws;                 // [0, 6690816)  (B,66,66,768) over qb/kb/vb/rl/vs
  float* ao = ws + 6690816;               // [6690816, 8787968)  zeroed before attn2
  short* cb = (short*)(ws + 6690816);     // over ao (ao dead after k_proj)
  short* Wb = (short*)(ws + 8787968);     // [8787968, 9672704)
  // high-water: 9,672,704 floats = 38.7 MB

  k_qkv_mfma<<<dim3(64, 3, BB), 256, 0, stream>>>(src, tgt, Wq, bq, Wk, bk, Wv, bv, qb, kb, vb);
  hipMemsetAsync(rl, 0, (size_t)BB * HW * 4, stream);
  k_lsum2<<<dim3(64, 4, BB), 256, 0, stream>>>(qb, kb, rl);
  k_vs   <<<dim3(2048),      256, 0, stream>>>(vb, rl, vs);
  hipMemsetAsync(ao, 0, (size_t)2097152 * 4, stream);
  k_attn2<<<dim3(64, 2, BB), 256, 0, stream>>>(qb, kb, vs, ao);
  // Xn overlaps qb/kb/vb/rl/vs -> zero only after k_attn2 (also zeroes guard ring)
  hipMemsetAsync(Xn, 0, (size_t)BB * 66 * 66 * 768 * 2, stream);
  k_proj <<<dim3(64, 2, BB), 256, 0, stream>>>(ao, tgt, Wp, bp, gamma, Xn);
  k_pack <<<dim3(64, 8, BB), 256, 0, stream>>>(prev, Xn);
  k_wb   <<<dim3(6912),      256, 0, stream>>>(Wc, Wb);
  k_conv_mfma<<<dim3(64, 2, BB), 256, 0, stream>>>(Xn, Wb, bcw, cb);
  k_inorm<<<dim3(1024),      256, 0, stream>>>(cb, (float*)d_out);
}